// Round 1
// baseline (1445.729 us; speedup 1.0000x reference)
//
#include <hip/hip_runtime.h>
#include <cstdint>
#include <cstddef>

// ---------- common ----------
typedef unsigned short u16;
typedef __bf16 bf16x8 __attribute__((ext_vector_type(8)));
typedef float f32x4 __attribute__((ext_vector_type(4)));

typedef const __attribute__((address_space(1))) void* gas_ptr;
typedef __attribute__((address_space(3))) void* las_ptr;
#define GLDS(gp, lp) __builtin_amdgcn_global_load_lds((gas_ptr)(gp), (las_ptr)(lp), 16, 0, 0)

__device__ __forceinline__ u16 f2bf(float f) {
  union { float f; uint32_t u; } a; a.f = f;
  uint32_t u = a.u;
  return (u16)((u + 0x7FFFu + ((u >> 16) & 1u)) >> 16);  // RNE, finite inputs
}
__device__ __forceinline__ float bf2f(u16 h) {
  union { uint32_t u; float f; } a; a.u = ((uint32_t)h) << 16;
  return a.f;
}

// dims
#define BB 2
#define SS 1024
#define HID 4096
#define NH 64
#define NKV 8
#define HD 192
#define VD 128
#define ROT 64
#define WINDOW 128
#define NQKV 14848            // NH*HD + NKV*HD + NKV*VD
#define SCALE 0.07216878364870323f
#define LOG2E 1.4426950408889634f

// ---------- f32 -> bf16 elementwise (X) ----------
__global__ void cvt_kernel(const float* __restrict__ src, u16* __restrict__ dst, int n4) {
  int i = blockIdx.x * 256 + threadIdx.x;
  if (i < n4) {
    float4 v = reinterpret_cast<const float4*>(src)[i];
    union { u16 h[4]; uint2 u; } o;
    o.h[0] = f2bf(v.x); o.h[1] = f2bf(v.y); o.h[2] = f2bf(v.z); o.h[3] = f2bf(v.w);
    reinterpret_cast<uint2*>(dst)[i] = o.u;
  }
}

// ---------- f32 RxC -> bf16 CxR transpose (weights -> B^T layout) ----------
__global__ void tr_kernel(const float* __restrict__ src, u16* __restrict__ dst, int R, int C) {
  __shared__ float tile[32][33];
  int r0 = blockIdx.y * 32, c0 = blockIdx.x * 32;
  int tx = threadIdx.x, ty = threadIdx.y;
  for (int i = ty; i < 32; i += 8)
    tile[i][tx] = src[(size_t)(r0 + i) * C + c0 + tx];
  __syncthreads();
  for (int i = ty; i < 32; i += 8)
    dst[(size_t)(c0 + i) * R + r0 + tx] = f2bf(tile[tx][i]);
}

// ---------- GEMM: C(MxN) = A(MxK,bf16) * Bt(NxK,bf16)^T ----------
// 128x128 tile, 4 waves (2x2 of 64x64), BK=32, m97 structure.
// LDS chunk layout: chunk(kq,row) @ (kq*128+row)*16B holds row's 8-bf16 k-subchunk kq.
template<bool BF16_OUT>
__global__ __launch_bounds__(256, 2)
void gemm_bt(const u16* __restrict__ A, const u16* __restrict__ Bt,
             void* __restrict__ Cout, int N, int K) {
  __shared__ alignas(16) char lds[16384];   // A: [0,8192), B: [8192,16384)
  const int tid  = threadIdx.x;
  const int wave = tid >> 6, lane = tid & 63;
  const int quad = lane >> 4, l16 = lane & 15;
  const int m0 = blockIdx.y * 128, n0 = blockIdx.x * 128;
  const int wm = (wave >> 1) * 64, wn = (wave & 1) * 64;

  const u16* Abase = A  + (size_t)m0 * K;
  const u16* Bbase = Bt + (size_t)n0 * K;

  f32x4 acc[4][4];
#pragma unroll
  for (int i = 0; i < 4; ++i)
#pragma unroll
    for (int j = 0; j < 4; ++j) acc[i][j] = f32x4{0.f, 0.f, 0.f, 0.f};

  for (int kt = 0; kt < K; kt += 32) {
    __syncthreads();
#pragma unroll
    for (int j = 0; j < 2; ++j) {
      int c  = wave * 128 + j * 64 + lane;   // chunk id 0..511
      int kq = c >> 7, row = c & 127;
      GLDS(Abase + (size_t)row * K + kt + kq * 8, &lds[(wave * 128 + j * 64) * 16]);
      GLDS(Bbase + (size_t)row * K + kt + kq * 8, &lds[8192 + (wave * 128 + j * 64) * 16]);
    }
    __syncthreads();
    bf16x8 af[4], bf[4];
#pragma unroll
    for (int i = 0; i < 4; ++i)
      af[i] = *reinterpret_cast<const bf16x8*>(&lds[(quad * 128 + wm + i * 16 + l16) * 16]);
#pragma unroll
    for (int j = 0; j < 4; ++j)
      bf[j] = *reinterpret_cast<const bf16x8*>(&lds[8192 + (quad * 128 + wn + j * 16 + l16) * 16]);
#pragma unroll
    for (int i = 0; i < 4; ++i)
#pragma unroll
      for (int j = 0; j < 4; ++j)
        acc[i][j] = __builtin_amdgcn_mfma_f32_16x16x32_bf16(af[i], bf[j], acc[i][j], 0, 0, 0);
  }

  // epilogue: C row = quad*4+r, col = l16 (verified m89/m91 layout)
  if constexpr (BF16_OUT) {
    u16* Co = reinterpret_cast<u16*>(Cout);
#pragma unroll
    for (int i = 0; i < 4; ++i)
#pragma unroll
      for (int j = 0; j < 4; ++j)
#pragma unroll
        for (int r = 0; r < 4; ++r)
          Co[(size_t)(m0 + wm + i * 16 + quad * 4 + r) * N + n0 + wn + j * 16 + l16] = f2bf(acc[i][j][r]);
  } else {
    float* Co = reinterpret_cast<float*>(Cout);
#pragma unroll
    for (int i = 0; i < 4; ++i)
#pragma unroll
      for (int j = 0; j < 4; ++j)
#pragma unroll
        for (int r = 0; r < 4; ++r)
          Co[(size_t)(m0 + wm + i * 16 + quad * 4 + r) * N + n0 + wn + j * 16 + l16] = acc[i][j][r];
  }
}

// ---------- RoPE + scatter QKV row -> Q(B,NH,S,HD) K(B,NKV,S,HD) Vt(B,NKV,VD,S) ----------
__global__ void rope_scatter(const u16* __restrict__ QKV, const float* __restrict__ cosb,
                             const float* __restrict__ sinb, u16* __restrict__ Qt,
                             u16* __restrict__ Kt, u16* __restrict__ Vt) {
  int row = blockIdx.x;                 // 0..2047 = b*1024+s
  int b = row >> 10, s = row & 1023;
  const u16* xr = QKV + (size_t)row * NQKV;
  const float* cr = cosb + (size_t)row * ROT;
  const float* sr = sinb + (size_t)row * ROT;

  for (int idx = threadIdx.x; idx < NH * HD; idx += 256) {
    int h = idx / HD, d = idx % HD;
    float x = bf2f(xr[idx]), val;
    if (d < 32)       val = x * cr[d] - bf2f(xr[idx + 32]) * sr[d];
    else if (d < 64)  val = x * cr[d] + bf2f(xr[idx - 32]) * sr[d];
    else              val = x;
    Qt[((size_t)(b * NH + h) * SS + s) * HD + d] = f2bf(val);
  }
  for (int idx = threadIdx.x; idx < NKV * HD; idx += 256) {
    int h = idx / HD, d = idx % HD;
    float x = bf2f(xr[NH * HD + idx]), val;
    if (d < 32)       val = x * cr[d] - bf2f(xr[NH * HD + idx + 32]) * sr[d];
    else if (d < 64)  val = x * cr[d] + bf2f(xr[NH * HD + idx - 32]) * sr[d];
    else              val = x;
    Kt[((size_t)(b * NKV + h) * SS + s) * HD + d] = f2bf(val);
  }
  for (int idx = threadIdx.x; idx < NKV * VD; idx += 256) {
    int h = idx >> 7, d = idx & 127;
    Vt[((size_t)(b * NKV + h) * VD + d) * SS + s] = xr[NH * HD + NKV * HD + idx];
  }
}

// ---------- attention: wg = (qtile16, hkv, b); 8 waves = 8 q-heads ----------
__global__ __launch_bounds__(512, 1)
void attn_kernel(const u16* __restrict__ Qt, const u16* __restrict__ Kt,
                 const u16* __restrict__ Vt, const float* __restrict__ sinks,
                 u16* __restrict__ Out) {
  __shared__ alignas(16) char vlds[40960];   // chunk(kq,d) @ (kq*128+d)*16, kq 0..19, d 0..127
  __shared__ alignas(16) char plds[8][1024]; // per-wave: chunk(kq,q) @ (kq*16+q)*16, kq 0..3
  __shared__ float llds[8][16];

  const int qt = blockIdx.x, hkv = blockIdx.y, b = blockIdx.z;
  const int tid = threadIdx.x;
  const int wave = tid >> 6, lane = tid & 63;
  const int quad = lane >> 4, l16 = lane & 15;
  const int h = hkv * 8 + wave;
  const int q0 = qt * 16, k0 = q0 - 128;

  // stage V window: 20 kq-chunks x 128 d = 2560 chunks of 16B
  const u16* Vb = Vt + (size_t)(b * NKV + hkv) * VD * SS;
  for (int it = 0; it < 5; ++it) {
    int c = (it * 8 + wave) * 64 + lane;
    int kq = c >> 7, d = c & 127;
    int s = k0 + kq * 8;
    s = min(max(s, 0), SS - 8);
    GLDS(Vb + (size_t)d * SS + s, &vlds[(it * 8 + wave) * 1024]);
  }
  // Q fragments (A-operand): lane holds Q[q=l16][k=quad*8+j] per 32-chunk
  const u16* Qb = Qt + ((size_t)(b * NH + h) * SS + q0) * HD;
  bf16x8 qf[6];
#pragma unroll
  for (int c = 0; c < 6; ++c)
    qf[c] = *reinterpret_cast<const bf16x8*>(Qb + (size_t)l16 * HD + c * 32 + quad * 8);
  const float sinkv = sinks[h];
  __syncthreads();

  // S = Q K^T : 9 key tiles of 16
  const u16* Kb = Kt + (size_t)(b * NKV + hkv) * SS * HD;
  f32x4 sc[9];
#pragma unroll
  for (int kt = 0; kt < 9; ++kt) {
    int key = k0 + kt * 16 + l16;
    int keyc = min(max(key, 0), SS - 1);
    const u16* Krow = Kb + (size_t)keyc * HD;
    f32x4 s4 = {0.f, 0.f, 0.f, 0.f};
#pragma unroll
    for (int c = 0; c < 6; ++c) {
      bf16x8 kf = *reinterpret_cast<const bf16x8*>(Krow + c * 32 + quad * 8);
      s4 = __builtin_amdgcn_mfma_f32_16x16x32_bf16(qf[c], kf, s4, 0, 0, 0);
    }
    sc[kt] = s4;
  }

  // softmax per row (row = q0 + quad*4 + r); sink folded into max & denom
#pragma unroll
  for (int r = 0; r < 4; ++r) {
    int q = q0 + quad * 4 + r;
    float mv = sinkv;
    float svs[9];
#pragma unroll
    for (int kt = 0; kt < 9; ++kt) {
      int key = k0 + kt * 16 + l16;
      bool valid = (key >= 0) && (key <= q) && (q - key < WINDOW);
      float sv = valid ? sc[kt][r] * SCALE : -3.0e38f;
      svs[kt] = sv;
      mv = fmaxf(mv, sv);
    }
#pragma unroll
    for (int off = 1; off < 16; off <<= 1) mv = fmaxf(mv, __shfl_xor(mv, off));
    float lsum = 0.f;
#pragma unroll
    for (int kt = 0; kt < 9; ++kt) {
      float p = exp2f((svs[kt] - mv) * LOG2E);
      sc[kt][r] = p;          // overwrite score with unnormalized prob
      lsum += p;
    }
#pragma unroll
    for (int off = 1; off < 16; off <<= 1) lsum += __shfl_xor(lsum, off);
    lsum += exp2f((sinkv - mv) * LOG2E);
    if (l16 == 0) llds[wave][quad * 4 + r] = lsum;
  }

  // O^T = V^T P^T over 5 key-chunks of 32 (tile 9 of P zero-padded)
  f32x4 oacc[8];
#pragma unroll
  for (int mt = 0; mt < 8; ++mt) oacc[mt] = f32x4{0.f, 0.f, 0.f, 0.f};
#pragma unroll
  for (int c = 0; c < 5; ++c) {
#pragma unroll
    for (int t = 0; t < 2; ++t) {
      int kt = 2 * c + t;
#pragma unroll
      for (int r = 0; r < 4; ++r) {
        float p = (kt < 9) ? sc[kt][r] : 0.f;
        int off = (((t * 2 + (l16 >> 3)) * 16 + quad * 4 + r) << 4) + ((l16 & 7) << 1);
        *reinterpret_cast<u16*>(&plds[wave][off]) = f2bf(p);
      }
    }
    // same-wave LDS ops execute in order: write->read safe without barrier
    bf16x8 pf = *reinterpret_cast<const bf16x8*>(&plds[wave][(quad * 16 + l16) << 4]);
#pragma unroll
    for (int mt = 0; mt < 8; ++mt) {
      bf16x8 vf = *reinterpret_cast<const bf16x8*>(&vlds[((c * 4 + quad) * 128 + mt * 16 + l16) << 4]);
      oacc[mt] = __builtin_amdgcn_mfma_f32_16x16x32_bf16(vf, pf, oacc[mt], 0, 0, 0);
    }
  }

  float rl = 1.0f / llds[wave][l16];
  u16* Ob = Out + ((size_t)(b * SS) + q0 + l16) * (NH * VD) + h * VD;
#pragma unroll
  for (int mt = 0; mt < 8; ++mt) {
    union { u16 h4[4]; uint2 u; } w;
#pragma unroll
    for (int r = 0; r < 4; ++r) w.h4[r] = f2bf(oacc[mt][r] * rl);
    *reinterpret_cast<uint2*>(Ob + mt * 16 + quad * 4) = w.u;
  }
}

// ---------- launch ----------
extern "C" void kernel_launch(void* const* d_in, const int* in_sizes, int n_in,
                              void* d_out, int out_size, void* d_ws, size_t ws_size,
                              hipStream_t stream) {
  const float* X     = (const float*)d_in[0];
  const float* cosb  = (const float*)d_in[1];
  const float* sinb  = (const float*)d_in[2];
  const float* Wq    = (const float*)d_in[3];
  const float* Wk    = (const float*)d_in[4];
  const float* Wv    = (const float*)d_in[5];
  const float* Wo    = (const float*)d_in[6];
  const float* sinks = (const float*)d_in[7];

  char* ws = (char*)d_ws;
  u16* Xb    = (u16*)(ws);                 // 16,777,216 B
  u16* WqkvT = (u16*)(ws + 16777216);      // 121,634,816 B
  u16* WoT   = (u16*)(ws);                 // reuses Xb/WqkvT region after GEMM1
  u16* QKV   = (u16*)(ws + 138412032);     // 60,817,408 B
  u16* Qt    = (u16*)(ws + 199229440);     // 50,331,648 B
  u16* Kt    = (u16*)(ws + 249561088);     // 6,291,456 B
  u16* Vt    = (u16*)(ws + 255852544);     // 4,194,304 B
  u16* attn  = (u16*)(ws + 260046848);     // 33,554,432 B  (total 293,601,280)

  cvt_kernel<<<8192, 256, 0, stream>>>(X, Xb, 2097152);
  tr_kernel<<<dim3(384, 128), dim3(32, 8), 0, stream>>>(Wq, WqkvT, HID, NH * HD);
  tr_kernel<<<dim3(48, 128),  dim3(32, 8), 0, stream>>>(Wk, WqkvT + (size_t)NH * HD * HID, HID, NKV * HD);
  tr_kernel<<<dim3(32, 128),  dim3(32, 8), 0, stream>>>(Wv, WqkvT + (size_t)(NH * HD + NKV * HD) * HID, HID, NKV * VD);
  gemm_bt<true><<<dim3(116, 16), 256, 0, stream>>>(Xb, WqkvT, QKV, NQKV, HID);
  tr_kernel<<<dim3(128, 256), dim3(32, 8), 0, stream>>>(Wo, WoT, NH * VD, HID);
  rope_scatter<<<2048, 256, 0, stream>>>(QKV, cosb, sinb, Qt, Kt, Vt);
  attn_kernel<<<dim3(64, 8, 2), 512, 0, stream>>>(Qt, Kt, Vt, sinks, attn);
  gemm_bt<false><<<dim3(32, 16), 256, 0, stream>>>(attn, WoT, d_out, HID, NH * VD);
}

// Round 2
// 1399.741 us; speedup vs baseline: 1.0329x; 1.0329x over previous
//
#include <hip/hip_runtime.h>
#include <cstdint>
#include <cstddef>

// ---------- common ----------
typedef unsigned short u16;
typedef __bf16 bf16x8 __attribute__((ext_vector_type(8)));
typedef float f32x4 __attribute__((ext_vector_type(4)));

typedef const __attribute__((address_space(1))) void* gas_ptr;
typedef __attribute__((address_space(3))) void* las_ptr;
#define GLDS(gp, lp) __builtin_amdgcn_global_load_lds((gas_ptr)(gp), (las_ptr)(lp), 16, 0, 0)

__device__ __forceinline__ u16 f2bf(float f) {
  union { float f; uint32_t u; } a; a.f = f;
  uint32_t u = a.u;
  return (u16)((u + 0x7FFFu + ((u >> 16) & 1u)) >> 16);  // RNE, finite inputs
}
__device__ __forceinline__ float bf2f(u16 h) {
  union { uint32_t u; float f; } a; a.u = ((uint32_t)h) << 16;
  return a.f;
}

// dims
#define BB 2
#define SS 1024
#define HID 4096
#define NH 64
#define NKV 8
#define HD 192
#define VD 128
#define ROT 64
#define WINDOW 128
#define NQKV 14848            // NH*HD + NKV*HD + NKV*VD
#define SCALE 0.07216878364870323f
#define LOG2E 1.4426950408889634f

// ---------- f32 -> bf16 elementwise (X) ----------
__global__ void cvt_kernel(const float* __restrict__ src, u16* __restrict__ dst, int n4) {
  int i = blockIdx.x * 256 + threadIdx.x;
  if (i < n4) {
    float4 v = reinterpret_cast<const float4*>(src)[i];
    union { u16 h[4]; uint2 u; } o;
    o.h[0] = f2bf(v.x); o.h[1] = f2bf(v.y); o.h[2] = f2bf(v.z); o.h[3] = f2bf(v.w);
    reinterpret_cast<uint2*>(dst)[i] = o.u;
  }
}

// ---------- f32 RxC -> bf16 CxR transpose (weights -> B^T layout) ----------
__global__ void tr_kernel(const float* __restrict__ src, u16* __restrict__ dst, int R, int C) {
  __shared__ float tile[32][33];
  int r0 = blockIdx.y * 32, c0 = blockIdx.x * 32;
  int tx = threadIdx.x, ty = threadIdx.y;
  for (int i = ty; i < 32; i += 8)
    tile[i][tx] = src[(size_t)(r0 + i) * C + c0 + tx];
  __syncthreads();
  for (int i = ty; i < 32; i += 8)
    dst[(size_t)(c0 + i) * R + r0 + tx] = f2bf(tile[tx][i]);
}

// ---------- bf16 V-slice transpose: QKV rows -> Vt(B,NKV,VD,S) ----------
__global__ void vtr_kernel(const u16* __restrict__ QKV, u16* __restrict__ Vt) {
  __shared__ u16 tile[32][33];
  int d0 = blockIdx.x * 32;          // 0..96
  int s0 = blockIdx.y * 32;          // 0..992
  int bh = blockIdx.z;               // b*NKV+h
  int b = bh >> 3, h = bh & 7;
  int tx = threadIdx.x, ty = threadIdx.y;
  const u16* src = QKV + (size_t)(b * SS) * NQKV + (NH * HD + NKV * HD) + h * VD;
  for (int i = ty; i < 32; i += 8)
    tile[i][tx] = src[(size_t)(s0 + i) * NQKV + d0 + tx];
  __syncthreads();
  u16* dst = Vt + ((size_t)bh * VD) * SS;
  for (int i = ty; i < 32; i += 8)
    dst[(size_t)(d0 + i) * SS + s0 + tx] = tile[tx][i];
}

// ---------- GEMM: C(MxN) = A(MxK,bf16) * Bt(NxK,bf16)^T ----------
// 128x128 tile, 4 waves (2x2 of 64x64), BK=32, m97 structure.
// Grid: x = m-block (fastest) so co-resident blocks share B k-slices in L2/L3.
template<bool BF16_OUT>
__global__ __launch_bounds__(256, 2)
void gemm_bt(const u16* __restrict__ A, const u16* __restrict__ Bt,
             void* __restrict__ Cout, int N, int K) {
  __shared__ alignas(16) char lds[16384];   // A: [0,8192), B: [8192,16384)
  const int tid  = threadIdx.x;
  const int wave = tid >> 6, lane = tid & 63;
  const int quad = lane >> 4, l16 = lane & 15;
  const int m0 = blockIdx.x * 128, n0 = blockIdx.y * 128;
  const int wm = (wave >> 1) * 64, wn = (wave & 1) * 64;

  const u16* Abase = A  + (size_t)m0 * K;
  const u16* Bbase = Bt + (size_t)n0 * K;

  f32x4 acc[4][4];
#pragma unroll
  for (int i = 0; i < 4; ++i)
#pragma unroll
    for (int j = 0; j < 4; ++j) acc[i][j] = f32x4{0.f, 0.f, 0.f, 0.f};

  for (int kt = 0; kt < K; kt += 32) {
    __syncthreads();
#pragma unroll
    for (int j = 0; j < 2; ++j) {
      int c  = wave * 128 + j * 64 + lane;   // chunk id 0..511
      int kq = c >> 7, row = c & 127;
      GLDS(Abase + (size_t)row * K + kt + kq * 8, &lds[(wave * 128 + j * 64) * 16]);
      GLDS(Bbase + (size_t)row * K + kt + kq * 8, &lds[8192 + (wave * 128 + j * 64) * 16]);
    }
    __syncthreads();
    bf16x8 af[4], bf[4];
#pragma unroll
    for (int i = 0; i < 4; ++i)
      af[i] = *reinterpret_cast<const bf16x8*>(&lds[(quad * 128 + wm + i * 16 + l16) * 16]);
#pragma unroll
    for (int j = 0; j < 4; ++j)
      bf[j] = *reinterpret_cast<const bf16x8*>(&lds[8192 + (quad * 128 + wn + j * 16 + l16) * 16]);
#pragma unroll
    for (int i = 0; i < 4; ++i)
#pragma unroll
      for (int j = 0; j < 4; ++j)
        acc[i][j] = __builtin_amdgcn_mfma_f32_16x16x32_bf16(af[i], bf[j], acc[i][j], 0, 0, 0);
  }

  // epilogue: C row = quad*4+r, col = l16 (verified m89/m91 layout)
  if constexpr (BF16_OUT) {
    u16* Co = reinterpret_cast<u16*>(Cout);
#pragma unroll
    for (int i = 0; i < 4; ++i)
#pragma unroll
      for (int j = 0; j < 4; ++j)
#pragma unroll
        for (int r = 0; r < 4; ++r)
          Co[(size_t)(m0 + wm + i * 16 + quad * 4 + r) * N + n0 + wn + j * 16 + l16] = f2bf(acc[i][j][r]);
  } else {
    float* Co = reinterpret_cast<float*>(Cout);
#pragma unroll
    for (int i = 0; i < 4; ++i)
#pragma unroll
      for (int j = 0; j < 4; ++j)
#pragma unroll
        for (int r = 0; r < 4; ++r)
          Co[(size_t)(m0 + wm + i * 16 + quad * 4 + r) * N + n0 + wn + j * 16 + l16] = acc[i][j][r];
  }
}

// ---------- RoPE + scatter QK rows -> Q(B,NH,S,HD) K(B,NKV,S,HD) ----------
__global__ void rope_scatter(const u16* __restrict__ QKV, const float* __restrict__ cosb,
                             const float* __restrict__ sinb, u16* __restrict__ Qt,
                             u16* __restrict__ Kt) {
  int row = blockIdx.x;                 // 0..2047 = b*1024+s
  int b = row >> 10, s = row & 1023;
  const u16* xr = QKV + (size_t)row * NQKV;
  const float* cr = cosb + (size_t)row * ROT;
  const float* sr = sinb + (size_t)row * ROT;

  for (int idx = threadIdx.x; idx < NH * HD; idx += 256) {
    int h = idx / HD, d = idx % HD;
    float x = bf2f(xr[idx]), val;
    if (d < 32)       val = x * cr[d] - bf2f(xr[idx + 32]) * sr[d];
    else if (d < 64)  val = x * cr[d] + bf2f(xr[idx - 32]) * sr[d];
    else              val = x;
    Qt[((size_t)(b * NH + h) * SS + s) * HD + d] = f2bf(val);
  }
  for (int idx = threadIdx.x; idx < NKV * HD; idx += 256) {
    int h = idx / HD, d = idx % HD;
    float x = bf2f(xr[NH * HD + idx]), val;
    if (d < 32)       val = x * cr[d] - bf2f(xr[NH * HD + idx + 32]) * sr[d];
    else if (d < 64)  val = x * cr[d] + bf2f(xr[NH * HD + idx - 32]) * sr[d];
    else              val = x;
    Kt[((size_t)(b * NKV + h) * SS + s) * HD + d] = f2bf(val);
  }
}

// ---------- attention: wg = (qtile16, hkv, b); 8 waves = 8 q-heads ----------
__global__ __launch_bounds__(512, 1)
void attn_kernel(const u16* __restrict__ Qt, const u16* __restrict__ Kt,
                 const u16* __restrict__ Vt, const float* __restrict__ sinks,
                 u16* __restrict__ Out) {
  __shared__ alignas(16) char vlds[40960];   // chunk(kq,d) @ (kq*128+d)*16, kq 0..19, d 0..127
  __shared__ alignas(16) char plds[8][1024]; // per-wave: chunk(kq,q) @ (kq*16+q)*16, kq 0..3
  __shared__ float llds[8][16];

  const int qt = blockIdx.x, hkv = blockIdx.y, b = blockIdx.z;
  const int tid = threadIdx.x;
  const int wave = tid >> 6, lane = tid & 63;
  const int quad = lane >> 4, l16 = lane & 15;
  const int h = hkv * 8 + wave;
  const int q0 = qt * 16, k0 = q0 - 128;

  // stage V window: 20 kq-chunks x 128 d = 2560 chunks of 16B
  const u16* Vb = Vt + (size_t)(b * NKV + hkv) * VD * SS;
  for (int it = 0; it < 5; ++it) {
    int c = (it * 8 + wave) * 64 + lane;
    int kq = c >> 7, d = c & 127;
    int s = k0 + kq * 8;
    s = min(max(s, 0), SS - 8);
    GLDS(Vb + (size_t)d * SS + s, &vlds[(it * 8 + wave) * 1024]);
  }
  // Q fragments (A-operand): lane holds Q[q=l16][k=quad*8+j] per 32-chunk
  const u16* Qb = Qt + ((size_t)(b * NH + h) * SS + q0) * HD;
  bf16x8 qf[6];
#pragma unroll
  for (int c = 0; c < 6; ++c)
    qf[c] = *reinterpret_cast<const bf16x8*>(Qb + (size_t)l16 * HD + c * 32 + quad * 8);
  const float sinkv = sinks[h];
  __syncthreads();

  // S = Q K^T : 9 key tiles of 16
  const u16* Kb = Kt + (size_t)(b * NKV + hkv) * SS * HD;
  f32x4 sc[9];
#pragma unroll
  for (int kt = 0; kt < 9; ++kt) {
    int key = k0 + kt * 16 + l16;
    int keyc = min(max(key, 0), SS - 1);
    const u16* Krow = Kb + (size_t)keyc * HD;
    f32x4 s4 = {0.f, 0.f, 0.f, 0.f};
#pragma unroll
    for (int c = 0; c < 6; ++c) {
      bf16x8 kf = *reinterpret_cast<const bf16x8*>(Krow + c * 32 + quad * 8);
      s4 = __builtin_amdgcn_mfma_f32_16x16x32_bf16(qf[c], kf, s4, 0, 0, 0);
    }
    sc[kt] = s4;
  }

  // softmax per row (row = q0 + quad*4 + r); sink folded into max & denom
#pragma unroll
  for (int r = 0; r < 4; ++r) {
    int q = q0 + quad * 4 + r;
    float mv = sinkv;
    float svs[9];
#pragma unroll
    for (int kt = 0; kt < 9; ++kt) {
      int key = k0 + kt * 16 + l16;
      bool valid = (key >= 0) && (key <= q) && (q - key < WINDOW);
      float sv = valid ? sc[kt][r] * SCALE : -3.0e38f;
      svs[kt] = sv;
      mv = fmaxf(mv, sv);
    }
#pragma unroll
    for (int off = 1; off < 16; off <<= 1) mv = fmaxf(mv, __shfl_xor(mv, off));
    float lsum = 0.f;
#pragma unroll
    for (int kt = 0; kt < 9; ++kt) {
      float p = exp2f((svs[kt] - mv) * LOG2E);
      sc[kt][r] = p;          // overwrite score with unnormalized prob
      lsum += p;
    }
#pragma unroll
    for (int off = 1; off < 16; off <<= 1) lsum += __shfl_xor(lsum, off);
    lsum += exp2f((sinkv - mv) * LOG2E);
    if (l16 == 0) llds[wave][quad * 4 + r] = lsum;
  }

  // O^T = V^T P^T over 5 key-chunks of 32 (tile 9 of P zero-padded)
  f32x4 oacc[8];
#pragma unroll
  for (int mt = 0; mt < 8; ++mt) oacc[mt] = f32x4{0.f, 0.f, 0.f, 0.f};
#pragma unroll
  for (int c = 0; c < 5; ++c) {
#pragma unroll
    for (int t = 0; t < 2; ++t) {
      int kt = 2 * c + t;
#pragma unroll
      for (int r = 0; r < 4; ++r) {
        float p = (kt < 9) ? sc[kt][r] : 0.f;
        int off = (((t * 2 + (l16 >> 3)) * 16 + quad * 4 + r) << 4) + ((l16 & 7) << 1);
        *reinterpret_cast<u16*>(&plds[wave][off]) = f2bf(p);
      }
    }
    // same-wave LDS ops execute in order: write->read safe without barrier
    bf16x8 pf = *reinterpret_cast<const bf16x8*>(&plds[wave][(quad * 16 + l16) << 4]);
#pragma unroll
    for (int mt = 0; mt < 8; ++mt) {
      bf16x8 vf = *reinterpret_cast<const bf16x8*>(&vlds[((c * 4 + quad) * 128 + mt * 16 + l16) << 4]);
      oacc[mt] = __builtin_amdgcn_mfma_f32_16x16x32_bf16(vf, pf, oacc[mt], 0, 0, 0);
    }
  }

  float rl = 1.0f / llds[wave][l16];
  u16* Ob = Out + ((size_t)(b * SS) + q0 + l16) * (NH * VD) + h * VD;
#pragma unroll
  for (int mt = 0; mt < 8; ++mt) {
    union { u16 h4[4]; uint2 u; } w;
#pragma unroll
    for (int r = 0; r < 4; ++r) w.h4[r] = f2bf(oacc[mt][r] * rl);
    *reinterpret_cast<uint2*>(Ob + mt * 16 + quad * 4) = w.u;
  }
}

// ---------- launch ----------
extern "C" void kernel_launch(void* const* d_in, const int* in_sizes, int n_in,
                              void* d_out, int out_size, void* d_ws, size_t ws_size,
                              hipStream_t stream) {
  const float* X     = (const float*)d_in[0];
  const float* cosb  = (const float*)d_in[1];
  const float* sinb  = (const float*)d_in[2];
  const float* Wq    = (const float*)d_in[3];
  const float* Wk    = (const float*)d_in[4];
  const float* Wv    = (const float*)d_in[5];
  const float* Wo    = (const float*)d_in[6];
  const float* sinks = (const float*)d_in[7];

  char* ws = (char*)d_ws;
  u16* Xb    = (u16*)(ws);                 // 16,777,216 B
  u16* WqkvT = (u16*)(ws + 16777216);      // 121,634,816 B
  u16* WoT   = (u16*)(ws);                 // reuses Xb/WqkvT region after GEMM1
  u16* QKV   = (u16*)(ws + 138412032);     // 60,817,408 B
  u16* Qt    = (u16*)(ws + 199229440);     // 50,331,648 B
  u16* Kt    = (u16*)(ws + 249561088);     // 6,291,456 B
  u16* Vt    = (u16*)(ws + 255852544);     // 4,194,304 B
  u16* attn  = (u16*)(ws + 260046848);     // 33,554,432 B  (total 293,601,280)

  cvt_kernel<<<8192, 256, 0, stream>>>(X, Xb, 2097152);
  tr_kernel<<<dim3(384, 128), dim3(32, 8), 0, stream>>>(Wq, WqkvT, HID, NH * HD);
  tr_kernel<<<dim3(48, 128),  dim3(32, 8), 0, stream>>>(Wk, WqkvT + (size_t)NH * HD * HID, HID, NKV * HD);
  tr_kernel<<<dim3(32, 128),  dim3(32, 8), 0, stream>>>(Wv, WqkvT + (size_t)(NH * HD + NKV * HD) * HID, HID, NKV * VD);
  gemm_bt<true><<<dim3(16, 116), 256, 0, stream>>>(Xb, WqkvT, QKV, NQKV, HID);
  tr_kernel<<<dim3(128, 256), dim3(32, 8), 0, stream>>>(Wo, WoT, NH * VD, HID);
  rope_scatter<<<2048, 256, 0, stream>>>(QKV, cosb, sinb, Qt, Kt);
  vtr_kernel<<<dim3(4, 32, 16), dim3(32, 8), 0, stream>>>(QKV, Vt);
  attn_kernel<<<dim3(64, 8, 2), 512, 0, stream>>>(Qt, Kt, Vt, sinks, attn);
  gemm_bt<false><<<dim3(16, 32), 256, 0, stream>>>(attn, WoT, d_out, HID, NH * VD);
}

// Round 3
// 1112.873 us; speedup vs baseline: 1.2991x; 1.2578x over previous
//
#include <hip/hip_runtime.h>
#include <cstdint>
#include <cstddef>

// ---------- common ----------
typedef unsigned short u16;
typedef __bf16 bf16x8 __attribute__((ext_vector_type(8)));
typedef float f32x4 __attribute__((ext_vector_type(4)));

typedef const __attribute__((address_space(1))) void* gas_ptr;
typedef __attribute__((address_space(3))) void* las_ptr;
#define GLDS(gp, lp) __builtin_amdgcn_global_load_lds((gas_ptr)(gp), (las_ptr)(lp), 16, 0, 0)

__device__ __forceinline__ u16 f2bf(float f) {
  union { float f; uint32_t u; } a; a.f = f;
  uint32_t u = a.u;
  return (u16)((u + 0x7FFFu + ((u >> 16) & 1u)) >> 16);  // RNE, finite inputs
}
__device__ __forceinline__ float bf2f(u16 h) {
  union { uint32_t u; float f; } a; a.u = ((uint32_t)h) << 16;
  return a.f;
}

// dims
#define BB 2
#define SS 1024
#define HID 4096
#define NH 64
#define NKV 8
#define HD 192
#define VD 128
#define ROT 64
#define WINDOW 128
#define NQKV 14848            // NH*HD + NKV*HD + NKV*VD
#define SCALE 0.07216878364870323f
#define LOG2E 1.4426950408889634f

// ---------- f32 -> bf16 elementwise (X) ----------
__global__ void cvt_kernel(const float* __restrict__ src, u16* __restrict__ dst, int n4) {
  int i = blockIdx.x * 256 + threadIdx.x;
  if (i < n4) {
    float4 v = reinterpret_cast<const float4*>(src)[i];
    union { u16 h[4]; uint2 u; } o;
    o.h[0] = f2bf(v.x); o.h[1] = f2bf(v.y); o.h[2] = f2bf(v.z); o.h[3] = f2bf(v.w);
    reinterpret_cast<uint2*>(dst)[i] = o.u;
  }
}

// ---------- f32 RxC -> bf16 CxR transpose (weights -> B^T layout) ----------
__global__ void tr_kernel(const float* __restrict__ src, u16* __restrict__ dst, int R, int C) {
  __shared__ float tile[32][33];
  int r0 = blockIdx.y * 32, c0 = blockIdx.x * 32;
  int tx = threadIdx.x, ty = threadIdx.y;
  for (int i = ty; i < 32; i += 8)
    tile[i][tx] = src[(size_t)(r0 + i) * C + c0 + tx];
  __syncthreads();
  for (int i = ty; i < 32; i += 8)
    dst[(size_t)(c0 + i) * R + r0 + tx] = f2bf(tile[tx][i]);
}

// ---------- bf16 V-slice transpose: QKV rows -> Vt(B,NKV,VD,S) ----------
__global__ void vtr_kernel(const u16* __restrict__ QKV, u16* __restrict__ Vt) {
  __shared__ u16 tile[32][33];
  int d0 = blockIdx.x * 32;          // 0..96
  int s0 = blockIdx.y * 32;          // 0..992
  int bh = blockIdx.z;               // b*NKV+h
  int b = bh >> 3, h = bh & 7;
  int tx = threadIdx.x, ty = threadIdx.y;
  const u16* src = QKV + (size_t)(b * SS) * NQKV + (NH * HD + NKV * HD) + h * VD;
  for (int i = ty; i < 32; i += 8)
    tile[i][tx] = src[(size_t)(s0 + i) * NQKV + d0 + tx];
  __syncthreads();
  u16* dst = Vt + ((size_t)bh * VD) * SS;
  for (int i = ty; i < 32; i += 8)
    dst[(size_t)(d0 + i) * SS + s0 + tx] = tile[tx][i];
}

// ---------- GEMM: C(MxN) = A(MxK,bf16) * Bt(NxK,bf16)^T ----------
// 128x128 tile, 4 waves (2x2 of 64x64), BK=32.
// Staging: coalesced GLDS — 4 consecutive lanes fetch one row's 64B k-slice
// (16 lines/instr, ideal). LDS chunk layout [row][kq] with kq ^= (row>>2)&3
// swizzle -> 2-way bank aliasing on read (free per m136).
// Grid: x = m-block (fastest) so co-resident blocks share B k-slices in L2/L3.
template<bool BF16_OUT>
__global__ __launch_bounds__(256, 2)
void gemm_bt(const u16* __restrict__ A, const u16* __restrict__ Bt,
             void* __restrict__ Cout, int N, int K) {
  __shared__ alignas(16) char lds[16384];   // A: [0,8192), B: [8192,16384)
  const int tid  = threadIdx.x;
  const int wave = tid >> 6, lane = tid & 63;
  const int quad = lane >> 4, l16 = lane & 15;
  const int m0 = blockIdx.x * 128, n0 = blockIdx.y * 128;
  const int wm = (wave >> 1) * 64, wn = (wave & 1) * 64;

  const u16* Abase = A  + (size_t)m0 * K;
  const u16* Bbase = Bt + (size_t)n0 * K;

  f32x4 acc[4][4];
#pragma unroll
  for (int i = 0; i < 4; ++i)
#pragma unroll
    for (int j = 0; j < 4; ++j) acc[i][j] = f32x4{0.f, 0.f, 0.f, 0.f};

  for (int kt = 0; kt < K; kt += 32) {
    __syncthreads();
#pragma unroll
    for (int j = 0; j < 2; ++j) {
      int c   = wave * 128 + j * 64 + lane;   // LDS chunk id 0..511
      int row = c >> 2;                       // tile row 0..127
      int kq  = (lane & 3) ^ ((row >> 2) & 3);
      GLDS(Abase + (size_t)row * K + kt + kq * 8, &lds[(wave * 128 + j * 64) * 16]);
      GLDS(Bbase + (size_t)row * K + kt + kq * 8, &lds[8192 + (wave * 128 + j * 64) * 16]);
    }
    __syncthreads();
    bf16x8 af[4], bf[4];
#pragma unroll
    for (int i = 0; i < 4; ++i) {
      int r = wm + i * 16 + l16;
      af[i] = *reinterpret_cast<const bf16x8*>(&lds[(r * 4 + (quad ^ ((r >> 2) & 3))) * 16]);
    }
#pragma unroll
    for (int j = 0; j < 4; ++j) {
      int r = wn + j * 16 + l16;
      bf[j] = *reinterpret_cast<const bf16x8*>(&lds[8192 + (r * 4 + (quad ^ ((r >> 2) & 3))) * 16]);
    }
#pragma unroll
    for (int i = 0; i < 4; ++i)
#pragma unroll
      for (int j = 0; j < 4; ++j)
        acc[i][j] = __builtin_amdgcn_mfma_f32_16x16x32_bf16(af[i], bf[j], acc[i][j], 0, 0, 0);
  }

  // epilogue: C row = quad*4+r, col = l16 (verified m89/m91 layout)
  if constexpr (BF16_OUT) {
    u16* Co = reinterpret_cast<u16*>(Cout);
#pragma unroll
    for (int i = 0; i < 4; ++i)
#pragma unroll
      for (int j = 0; j < 4; ++j)
#pragma unroll
        for (int r = 0; r < 4; ++r)
          Co[(size_t)(m0 + wm + i * 16 + quad * 4 + r) * N + n0 + wn + j * 16 + l16] = f2bf(acc[i][j][r]);
  } else {
    float* Co = reinterpret_cast<float*>(Cout);
#pragma unroll
    for (int i = 0; i < 4; ++i)
#pragma unroll
      for (int j = 0; j < 4; ++j)
#pragma unroll
        for (int r = 0; r < 4; ++r)
          Co[(size_t)(m0 + wm + i * 16 + quad * 4 + r) * N + n0 + wn + j * 16 + l16] = acc[i][j][r];
  }
}

// ---------- RoPE + scatter QK rows -> Q(B,NH,S,HD) K(B,NKV,S,HD) ----------
__global__ void rope_scatter(const u16* __restrict__ QKV, const float* __restrict__ cosb,
                             const float* __restrict__ sinb, u16* __restrict__ Qt,
                             u16* __restrict__ Kt) {
  int row = blockIdx.x;                 // 0..2047 = b*1024+s
  int b = row >> 10, s = row & 1023;
  const u16* xr = QKV + (size_t)row * NQKV;
  const float* cr = cosb + (size_t)row * ROT;
  const float* sr = sinb + (size_t)row * ROT;

  for (int idx = threadIdx.x; idx < NH * HD; idx += 256) {
    int h = idx / HD, d = idx % HD;
    float x = bf2f(xr[idx]), val;
    if (d < 32)       val = x * cr[d] - bf2f(xr[idx + 32]) * sr[d];
    else if (d < 64)  val = x * cr[d] + bf2f(xr[idx - 32]) * sr[d];
    else              val = x;
    Qt[((size_t)(b * NH + h) * SS + s) * HD + d] = f2bf(val);
  }
  for (int idx = threadIdx.x; idx < NKV * HD; idx += 256) {
    int h = idx / HD, d = idx % HD;
    float x = bf2f(xr[NH * HD + idx]), val;
    if (d < 32)       val = x * cr[d] - bf2f(xr[NH * HD + idx + 32]) * sr[d];
    else if (d < 64)  val = x * cr[d] + bf2f(xr[NH * HD + idx - 32]) * sr[d];
    else              val = x;
    Kt[((size_t)(b * NKV + h) * SS + s) * HD + d] = f2bf(val);
  }
}

// ---------- attention: wg = (qtile16, hkv, b); 8 waves = 8 q-heads ----------
__global__ __launch_bounds__(512, 1)
void attn_kernel(const u16* __restrict__ Qt, const u16* __restrict__ Kt,
                 const u16* __restrict__ Vt, const float* __restrict__ sinks,
                 u16* __restrict__ Out) {
  __shared__ alignas(16) char vlds[40960];   // chunk(kq,d) @ (kq*128+d)*16, kq 0..19, d 0..127
  __shared__ alignas(16) char plds[8][1024]; // per-wave: chunk(kq,q) @ (kq*16+q)*16, kq 0..3
  __shared__ float llds[8][16];

  const int qt = blockIdx.x, hkv = blockIdx.y, b = blockIdx.z;
  const int tid = threadIdx.x;
  const int wave = tid >> 6, lane = tid & 63;
  const int quad = lane >> 4, l16 = lane & 15;
  const int h = hkv * 8 + wave;
  const int q0 = qt * 16, k0 = q0 - 128;

  // stage V window: 20 kq-chunks x 128 d = 2560 chunks of 16B
  const u16* Vb = Vt + (size_t)(b * NKV + hkv) * VD * SS;
  for (int it = 0; it < 5; ++it) {
    int c = (it * 8 + wave) * 64 + lane;
    int kq = c >> 7, d = c & 127;
    int s = k0 + kq * 8;
    s = min(max(s, 0), SS - 8);
    GLDS(Vb + (size_t)d * SS + s, &vlds[(it * 8 + wave) * 1024]);
  }
  // Q fragments (A-operand): lane holds Q[q=l16][k=quad*8+j] per 32-chunk
  const u16* Qb = Qt + ((size_t)(b * NH + h) * SS + q0) * HD;
  bf16x8 qf[6];
#pragma unroll
  for (int c = 0; c < 6; ++c)
    qf[c] = *reinterpret_cast<const bf16x8*>(Qb + (size_t)l16 * HD + c * 32 + quad * 8);
  const float sinkv = sinks[h];
  __syncthreads();

  // S = Q K^T : 9 key tiles of 16
  const u16* Kb = Kt + (size_t)(b * NKV + hkv) * SS * HD;
  f32x4 sc[9];
#pragma unroll
  for (int kt = 0; kt < 9; ++kt) {
    int key = k0 + kt * 16 + l16;
    int keyc = min(max(key, 0), SS - 1);
    const u16* Krow = Kb + (size_t)keyc * HD;
    f32x4 s4 = {0.f, 0.f, 0.f, 0.f};
#pragma unroll
    for (int c = 0; c < 6; ++c) {
      bf16x8 kf = *reinterpret_cast<const bf16x8*>(Krow + c * 32 + quad * 8);
      s4 = __builtin_amdgcn_mfma_f32_16x16x32_bf16(qf[c], kf, s4, 0, 0, 0);
    }
    sc[kt] = s4;
  }

  // softmax per row (row = q0 + quad*4 + r); sink folded into max & denom
#pragma unroll
  for (int r = 0; r < 4; ++r) {
    int q = q0 + quad * 4 + r;
    float mv = sinkv;
    float svs[9];
#pragma unroll
    for (int kt = 0; kt < 9; ++kt) {
      int key = k0 + kt * 16 + l16;
      bool valid = (key >= 0) && (key <= q) && (q - key < WINDOW);
      float sv = valid ? sc[kt][r] * SCALE : -3.0e38f;
      svs[kt] = sv;
      mv = fmaxf(mv, sv);
    }
#pragma unroll
    for (int off = 1; off < 16; off <<= 1) mv = fmaxf(mv, __shfl_xor(mv, off));
    float lsum = 0.f;
#pragma unroll
    for (int kt = 0; kt < 9; ++kt) {
      float p = exp2f((svs[kt] - mv) * LOG2E);
      sc[kt][r] = p;          // overwrite score with unnormalized prob
      lsum += p;
    }
#pragma unroll
    for (int off = 1; off < 16; off <<= 1) lsum += __shfl_xor(lsum, off);
    lsum += exp2f((sinkv - mv) * LOG2E);
    if (l16 == 0) llds[wave][quad * 4 + r] = lsum;
  }

  // O^T = V^T P^T over 5 key-chunks of 32 (tile 9 of P zero-padded)
  f32x4 oacc[8];
#pragma unroll
  for (int mt = 0; mt < 8; ++mt) oacc[mt] = f32x4{0.f, 0.f, 0.f, 0.f};
#pragma unroll
  for (int c = 0; c < 5; ++c) {
#pragma unroll
    for (int t = 0; t < 2; ++t) {
      int kt = 2 * c + t;
#pragma unroll
      for (int r = 0; r < 4; ++r) {
        float p = (kt < 9) ? sc[kt][r] : 0.f;
        int off = (((t * 2 + (l16 >> 3)) * 16 + quad * 4 + r) << 4) + ((l16 & 7) << 1);
        *reinterpret_cast<u16*>(&plds[wave][off]) = f2bf(p);
      }
    }
    // same-wave LDS ops execute in order: write->read safe without barrier
    bf16x8 pf = *reinterpret_cast<const bf16x8*>(&plds[wave][(quad * 16 + l16) << 4]);
#pragma unroll
    for (int mt = 0; mt < 8; ++mt) {
      bf16x8 vf = *reinterpret_cast<const bf16x8*>(&vlds[((c * 4 + quad) * 128 + mt * 16 + l16) << 4]);
      oacc[mt] = __builtin_amdgcn_mfma_f32_16x16x32_bf16(vf, pf, oacc[mt], 0, 0, 0);
    }
  }

  float rl = 1.0f / llds[wave][l16];
  u16* Ob = Out + ((size_t)(b * SS) + q0 + l16) * (NH * VD) + h * VD;
#pragma unroll
  for (int mt = 0; mt < 8; ++mt) {
    union { u16 h4[4]; uint2 u; } w;
#pragma unroll
    for (int r = 0; r < 4; ++r) w.h4[r] = f2bf(oacc[mt][r] * rl);
    *reinterpret_cast<uint2*>(Ob + mt * 16 + quad * 4) = w.u;
  }
}

// ---------- launch ----------
extern "C" void kernel_launch(void* const* d_in, const int* in_sizes, int n_in,
                              void* d_out, int out_size, void* d_ws, size_t ws_size,
                              hipStream_t stream) {
  const float* X     = (const float*)d_in[0];
  const float* cosb  = (const float*)d_in[1];
  const float* sinb  = (const float*)d_in[2];
  const float* Wq    = (const float*)d_in[3];
  const float* Wk    = (const float*)d_in[4];
  const float* Wv    = (const float*)d_in[5];
  const float* Wo    = (const float*)d_in[6];
  const float* sinks = (const float*)d_in[7];

  char* ws = (char*)d_ws;
  u16* Xb    = (u16*)(ws);                 // 16,777,216 B
  u16* WqkvT = (u16*)(ws + 16777216);      // 121,634,816 B
  u16* WoT   = (u16*)(ws);                 // reuses Xb/WqkvT region after GEMM1
  u16* QKV   = (u16*)(ws + 138412032);     // 60,817,408 B
  u16* Qt    = (u16*)(ws + 199229440);     // 50,331,648 B
  u16* Kt    = (u16*)(ws + 249561088);     // 6,291,456 B
  u16* Vt    = (u16*)(ws + 255852544);     // 4,194,304 B
  u16* attn  = (u16*)(ws + 260046848);     // 33,554,432 B  (total 293,601,280)

  cvt_kernel<<<8192, 256, 0, stream>>>(X, Xb, 2097152);
  tr_kernel<<<dim3(384, 128), dim3(32, 8), 0, stream>>>(Wq, WqkvT, HID, NH * HD);
  tr_kernel<<<dim3(48, 128),  dim3(32, 8), 0, stream>>>(Wk, WqkvT + (size_t)NH * HD * HID, HID, NKV * HD);
  tr_kernel<<<dim3(32, 128),  dim3(32, 8), 0, stream>>>(Wv, WqkvT + (size_t)(NH * HD + NKV * HD) * HID, HID, NKV * VD);
  gemm_bt<true><<<dim3(16, 116), 256, 0, stream>>>(Xb, WqkvT, QKV, NQKV, HID);
  tr_kernel<<<dim3(128, 256), dim3(32, 8), 0, stream>>>(Wo, WoT, NH * VD, HID);
  rope_scatter<<<2048, 256, 0, stream>>>(QKV, cosb, sinb, Qt, Kt);
  vtr_kernel<<<dim3(4, 32, 16), dim3(32, 8), 0, stream>>>(QKV, Vt);
  attn_kernel<<<dim3(64, 8, 2), 512, 0, stream>>>(Qt, Kt, Vt, sinks, attn);
  gemm_bt<false><<<dim3(16, 32), 256, 0, stream>>>(attn, WoT, d_out, HID, NH * VD);
}

// Round 4
// 1074.288 us; speedup vs baseline: 1.3458x; 1.0359x over previous
//
#include <hip/hip_runtime.h>
#include <cstdint>
#include <cstddef>

// ---------- common ----------
typedef unsigned short u16;
typedef __bf16 bf16x8 __attribute__((ext_vector_type(8)));
typedef unsigned short u16x8 __attribute__((ext_vector_type(8)));
typedef float f32x4 __attribute__((ext_vector_type(4)));

typedef const __attribute__((address_space(1))) void* gas_ptr;
typedef __attribute__((address_space(3))) void* las_ptr;
#define GLDS(gp, lp) __builtin_amdgcn_global_load_lds((gas_ptr)(gp), (las_ptr)(lp), 16, 0, 0)

__device__ __forceinline__ u16 f2bf(float f) {
  union { float f; uint32_t u; } a; a.f = f;
  uint32_t u = a.u;
  return (u16)((u + 0x7FFFu + ((u >> 16) & 1u)) >> 16);  // RNE, finite inputs
}
__device__ __forceinline__ float bf2f(u16 h) {
  union { uint32_t u; float f; } a; a.u = ((uint32_t)h) << 16;
  return a.f;
}

// dims
#define BB 2
#define SS 1024
#define HID 4096
#define NH 64
#define NKV 8
#define HD 192
#define VD 128
#define ROT 64
#define WINDOW 128
#define NQKV 14848            // NH*HD + NKV*HD + NKV*VD
#define SCALE 0.07216878364870323f
#define LOG2E 1.4426950408889634f

// Chunked operand layout: tile = 128 rows x 32 k (8192 B), tile (tr,tk) at
// (tr*nkt + tk)*8192 B; within tile chunk c = kq*128 + row (16 B = 8 bf16 of
// row `row`, k = kq*8..+8). MFMA fragment (row r, kq q) = contiguous 16 B.

// ---------- X (f32 MxK) -> chunked bf16 ----------
__global__ __launch_bounds__(256)
void chunk_cvt(const float* __restrict__ src, u16* __restrict__ dst, int K) {
  const int tr = blockIdx.x, tk = blockIdx.y;   // m-tile, k-tile
  const int nkt = K >> 5;
  const int m0 = tr * 128, k0 = tk * 32;
  u16* db = dst + ((size_t)tr * nkt + tk) * 4096;
#pragma unroll
  for (int p = 0; p < 4; ++p) {
    int idx = p * 256 + threadIdx.x;            // 0..1023
    int row = idx >> 3, f4 = idx & 7;
    float4 v = *reinterpret_cast<const float4*>(src + (size_t)(m0 + row) * K + k0 + f4 * 4);
    union { u16 h[4]; uint2 u; } o;
    o.h[0] = f2bf(v.x); o.h[1] = f2bf(v.y); o.h[2] = f2bf(v.z); o.h[3] = f2bf(v.w);
    int kq = f4 >> 1, half = f4 & 1;
    *reinterpret_cast<uint2*>(db + (kq * 128 + row) * 8 + half * 4) = o.u;
  }
}

// ---------- W (f32 RxC, R=K-dim) -> chunked bf16 B^T (C rows x R k) ----------
__global__ __launch_bounds__(256)
void chunk_tr(const float* __restrict__ src, u16* __restrict__ dst, int C, int nkt) {
  __shared__ float lf[32 * 128];                // [k][n] f32, 16 KB
  const int tn = blockIdx.x, tk = blockIdx.y;
  const int n0 = tn * 128, k0 = tk * 32;
#pragma unroll
  for (int p = 0; p < 4; ++p) {
    int idx = p * 256 + threadIdx.x;            // 0..1023
    int kr = idx >> 5, f4 = idx & 31;
    *reinterpret_cast<float4*>(&lf[kr * 128 + f4 * 4]) =
        *reinterpret_cast<const float4*>(src + (size_t)(k0 + kr) * C + n0 + f4 * 4);
  }
  __syncthreads();
  u16* db = dst + ((size_t)tn * nkt + tk) * 4096;
#pragma unroll
  for (int p = 0; p < 2; ++p) {
    int c = p * 256 + threadIdx.x;              // 0..511
    int kq = c >> 7, nl = c & 127;
    union { u16 h[8]; uint4 u; } o;
#pragma unroll
    for (int j = 0; j < 8; ++j) o.h[j] = f2bf(lf[(kq * 8 + j) * 128 + nl]);
    *reinterpret_cast<uint4*>(db + c * 8) = o.u;
  }
}

// ---------- V slices of QKV -> chunked Vc[bh][kq=s/8][d] ----------
__global__ __launch_bounds__(256)
void vtr_kernel(const u16* __restrict__ QKV, u16* __restrict__ Vc) {
  __shared__ u16 lt[64 * 72];                   // [s][d], pad 8 (row = 144 B, 16-mult)
  const int d0 = blockIdx.x * 64, sy = blockIdx.y, bh = blockIdx.z;
  const int b = bh >> 3, h = bh & 7;
  const int s0 = sy * 64;
  const u16* src = QKV + (size_t)(b * SS + s0) * NQKV + (NH * HD + NKV * HD) + h * VD + d0;
#pragma unroll
  for (int p = 0; p < 2; ++p) {
    int idx = p * 256 + threadIdx.x;            // 0..511
    int sl = idx >> 3, f8 = idx & 7;
    *reinterpret_cast<uint4*>(&lt[sl * 72 + f8 * 8]) =
        *reinterpret_cast<const uint4*>(src + (size_t)sl * NQKV + f8 * 8);
  }
  __syncthreads();
  u16* db = Vc + (size_t)bh * 131072;
#pragma unroll
  for (int p = 0; p < 2; ++p) {
    int c = p * 256 + threadIdx.x;              // 0..511
    int kql = c >> 6, dl = c & 63;
    union { u16 h[8]; uint4 u; } o;
#pragma unroll
    for (int j = 0; j < 8; ++j) o.h[j] = lt[(kql * 8 + j) * 72 + dl];
    *reinterpret_cast<uint4*>(db + ((sy * 8 + kql) * 128 + d0 + dl) * 8) = o.u;
  }
}

// ---------- GEMM: C(MxN) = A(chunked) * B(chunked)^T, no LDS, no barriers ----------
// 128x128 block tile, 4 waves (2x2 of 64x64). Fragments loaded directly from the
// chunked layout (4x256B contiguous per b128 instr); compiler pipelines via vmcnt.
template<bool BF16_OUT>
__global__ __launch_bounds__(256, 3)
void gemm_chunk(const u16* __restrict__ A, const u16* __restrict__ Bt,
                void* __restrict__ Cout, int N, int nkt) {
  const int tid  = threadIdx.x;
  const int wave = tid >> 6, lane = tid & 63;
  const int quad = lane >> 4, l16 = lane & 15;
  const int wm = (wave >> 1) * 64, wn = (wave & 1) * 64;
  const int m0 = blockIdx.x * 128, n0 = blockIdx.y * 128;

  const u16* Ab = A  + (size_t)blockIdx.x * nkt * 4096 + (quad * 128 + wm + l16) * 8;
  const u16* Bb = Bt + (size_t)blockIdx.y * nkt * 4096 + (quad * 128 + wn + l16) * 8;

  f32x4 acc[4][4];
#pragma unroll
  for (int i = 0; i < 4; ++i)
#pragma unroll
    for (int j = 0; j < 4; ++j) acc[i][j] = f32x4{0.f, 0.f, 0.f, 0.f};

#pragma unroll 2
  for (int kt = 0; kt < nkt; ++kt) {
    const u16* at = Ab + (size_t)kt * 4096;
    const u16* bt = Bb + (size_t)kt * 4096;
    bf16x8 af[4], bf[4];
#pragma unroll
    for (int i = 0; i < 4; ++i)
      af[i] = *reinterpret_cast<const bf16x8*>(at + i * 128);
#pragma unroll
    for (int j = 0; j < 4; ++j)
      bf[j] = *reinterpret_cast<const bf16x8*>(bt + j * 128);
#pragma unroll
    for (int i = 0; i < 4; ++i)
#pragma unroll
      for (int j = 0; j < 4; ++j)
        acc[i][j] = __builtin_amdgcn_mfma_f32_16x16x32_bf16(af[i], bf[j], acc[i][j], 0, 0, 0);
  }

  // epilogue: C row = quad*4+r, col = l16 (verified m89/m91 layout)
  if constexpr (BF16_OUT) {
    u16* Co = reinterpret_cast<u16*>(Cout);
#pragma unroll
    for (int i = 0; i < 4; ++i)
#pragma unroll
      for (int j = 0; j < 4; ++j)
#pragma unroll
        for (int r = 0; r < 4; ++r)
          Co[(size_t)(m0 + wm + i * 16 + quad * 4 + r) * N + n0 + wn + j * 16 + l16] = f2bf(acc[i][j][r]);
  } else {
    float* Co = reinterpret_cast<float*>(Cout);
#pragma unroll
    for (int i = 0; i < 4; ++i)
#pragma unroll
      for (int j = 0; j < 4; ++j)
#pragma unroll
        for (int r = 0; r < 4; ++r)
          Co[(size_t)(m0 + wm + i * 16 + quad * 4 + r) * N + n0 + wn + j * 16 + l16] = acc[i][j][r];
  }
}

// ---------- RoPE + scatter QK rows -> Q(B,NH,S,HD) K(B,NKV,S,HD), 16B chunks ----------
__global__ __launch_bounds__(256)
void rope_kernel(const u16* __restrict__ QKV, const float* __restrict__ cosb,
                 const float* __restrict__ sinb, u16* __restrict__ Qt,
                 u16* __restrict__ Kt) {
  const int row = blockIdx.x;           // b*1024+s
  const int b = row >> 10, s = row & 1023;
  const u16* xr = QKV + (size_t)row * NQKV;
  const float* cr = cosb + (size_t)row * ROT;
  const float* sr = sinb + (size_t)row * ROT;

  for (int u = threadIdx.x; u < (NH + NKV) * 24; u += 256) {
    const u16* srcb; u16* dstb; int c;
    if (u < NH * 24) {
      int h = u / 24; c = u - h * 24;
      srcb = xr + h * HD;
      dstb = Qt + ((size_t)(b * NH + h) * SS + s) * HD;
    } else {
      int v = u - NH * 24; int h = v / 24; c = v - h * 24;
      srcb = xr + NH * HD + h * HD;
      dstb = Kt + ((size_t)(b * NKV + h) * SS + s) * HD;
    }
    int d0 = c * 8;
    if (c < 8) {
      u16x8 xv = *reinterpret_cast<const u16x8*>(srcb + d0);
      u16x8 pv = *reinterpret_cast<const u16x8*>(srcb + ((c ^ 4) * 8));
      float4 c0 = *reinterpret_cast<const float4*>(cr + d0);
      float4 c1 = *reinterpret_cast<const float4*>(cr + d0 + 4);
      float4 s0 = *reinterpret_cast<const float4*>(sr + d0);
      float4 s1 = *reinterpret_cast<const float4*>(sr + d0 + 4);
      float cs[8] = {c0.x, c0.y, c0.z, c0.w, c1.x, c1.y, c1.z, c1.w};
      float sn[8] = {s0.x, s0.y, s0.z, s0.w, s1.x, s1.y, s1.z, s1.w};
      float sgn = (c < 4) ? -1.f : 1.f;
      union { u16 h[8]; uint4 u4; } o;
#pragma unroll
      for (int j = 0; j < 8; ++j)
        o.h[j] = f2bf(bf2f(xv[j]) * cs[j] + sgn * bf2f(pv[j]) * sn[j]);
      *reinterpret_cast<uint4*>(dstb + d0) = o.u4;
    } else {
      *reinterpret_cast<uint4*>(dstb + d0) = *reinterpret_cast<const uint4*>(srcb + d0);
    }
  }
}

// ---------- attention: wg = (qtile16, hkv, b); 8 waves = 8 q-heads ----------
// Out written in GEMM2's chunked-A layout.
__global__ __launch_bounds__(512, 1)
void attn_kernel(const u16* __restrict__ Qt, const u16* __restrict__ Kt,
                 const u16* __restrict__ Vc, const float* __restrict__ sinks,
                 u16* __restrict__ OutC) {
  __shared__ alignas(16) char vlds[40960];   // chunk(kq,d) @ (kq*128+d)*16, kq 0..19
  __shared__ alignas(16) char plds[8][1024]; // per-wave P fragment staging
  __shared__ float llds[8][16];

  const int qt = blockIdx.x, hkv = blockIdx.y, b = blockIdx.z;
  const int tid = threadIdx.x;
  const int wave = tid >> 6, lane = tid & 63;
  const int quad = lane >> 4, l16 = lane & 15;
  const int h = hkv * 8 + wave;
  const int q0 = qt * 16, k0 = q0 - 128;
  const int kq0 = (q0 - 128) >> 3;           // exact (q0 mult of 16)

  // stage V window: contiguous chunked copy (clamped at edges)
  const u16* Vb = Vc + (size_t)(b * NKV + hkv) * 131072;
  for (int it = 0; it < 5; ++it) {
    int c = (it * 8 + wave) * 64 + lane;     // 0..2559
    int kql = c >> 7, d = c & 127;
    int kqc = min(max(kq0 + kql, 0), 127);
    GLDS(Vb + (kqc * 128 + d) * 8, &vlds[(it * 8 + wave) * 1024]);
  }
  // Q fragments (A-operand): lane holds Q[q=l16][k=quad*8+j] per 32-chunk
  const u16* Qb = Qt + ((size_t)(b * NH + h) * SS + q0) * HD;
  bf16x8 qf[6];
#pragma unroll
  for (int c = 0; c < 6; ++c)
    qf[c] = *reinterpret_cast<const bf16x8*>(Qb + (size_t)l16 * HD + c * 32 + quad * 8);
  const float sinkv = sinks[h];
  __syncthreads();

  // S = Q K^T : 9 key tiles of 16
  const u16* Kb = Kt + (size_t)(b * NKV + hkv) * SS * HD;
  f32x4 sc[9];
#pragma unroll
  for (int kt = 0; kt < 9; ++kt) {
    int key = k0 + kt * 16 + l16;
    int keyc = min(max(key, 0), SS - 1);
    const u16* Krow = Kb + (size_t)keyc * HD;
    f32x4 s4 = {0.f, 0.f, 0.f, 0.f};
#pragma unroll
    for (int c = 0; c < 6; ++c) {
      bf16x8 kf = *reinterpret_cast<const bf16x8*>(Krow + c * 32 + quad * 8);
      s4 = __builtin_amdgcn_mfma_f32_16x16x32_bf16(qf[c], kf, s4, 0, 0, 0);
    }
    sc[kt] = s4;
  }

  // softmax per row (row = q0 + quad*4 + r); sink folded into max & denom
#pragma unroll
  for (int r = 0; r < 4; ++r) {
    int q = q0 + quad * 4 + r;
    float mv = sinkv;
    float svs[9];
#pragma unroll
    for (int kt = 0; kt < 9; ++kt) {
      int key = k0 + kt * 16 + l16;
      bool valid = (key >= 0) && (key <= q) && (q - key < WINDOW);
      float sv = valid ? sc[kt][r] * SCALE : -3.0e38f;
      svs[kt] = sv;
      mv = fmaxf(mv, sv);
    }
#pragma unroll
    for (int off = 1; off < 16; off <<= 1) mv = fmaxf(mv, __shfl_xor(mv, off));
    float lsum = 0.f;
#pragma unroll
    for (int kt = 0; kt < 9; ++kt) {
      float p = exp2f((svs[kt] - mv) * LOG2E);
      sc[kt][r] = p;
      lsum += p;
    }
#pragma unroll
    for (int off = 1; off < 16; off <<= 1) lsum += __shfl_xor(lsum, off);
    lsum += exp2f((sinkv - mv) * LOG2E);
    if (l16 == 0) llds[wave][quad * 4 + r] = lsum;
  }

  // O^T = V^T P^T over 5 key-chunks of 32 (tile 9 of P zero-padded)
  f32x4 oacc[8];
#pragma unroll
  for (int mt = 0; mt < 8; ++mt) oacc[mt] = f32x4{0.f, 0.f, 0.f, 0.f};
#pragma unroll
  for (int c = 0; c < 5; ++c) {
#pragma unroll
    for (int t = 0; t < 2; ++t) {
      int kt = 2 * c + t;
#pragma unroll
      for (int r = 0; r < 4; ++r) {
        float p = (kt < 9) ? sc[kt][r] : 0.f;
        int off = (((t * 2 + (l16 >> 3)) * 16 + quad * 4 + r) << 4) + ((l16 & 7) << 1);
        *reinterpret_cast<u16*>(&plds[wave][off]) = f2bf(p);
      }
    }
    // same-wave LDS ops execute in order: write->read safe without barrier
    bf16x8 pf = *reinterpret_cast<const bf16x8*>(&plds[wave][(quad * 16 + l16) << 4]);
#pragma unroll
    for (int mt = 0; mt < 8; ++mt) {
      bf16x8 vf = *reinterpret_cast<const bf16x8*>(&vlds[((c * 4 + quad) * 128 + mt * 16 + l16) << 4]);
      oacc[mt] = __builtin_amdgcn_mfma_f32_16x16x32_bf16(vf, pf, oacc[mt], 0, 0, 0);
    }
  }

  // write O into GEMM2's chunked-A layout (M=2048, K=8192, nkt=256)
  float rl = 1.0f / llds[wave][l16];
  int m = b * SS + q0 + l16;
  int tr = m >> 7, mrow = m & 127;
#pragma unroll
  for (int mt = 0; mt < 8; ++mt) {
    union { u16 h4[4]; uint2 u; } w;
#pragma unroll
    for (int r = 0; r < 4; ++r) w.h4[r] = f2bf(oacc[mt][r] * rl);
    int k = h * VD + mt * 16 + quad * 4;
    int tk = k >> 5, kq = (k >> 3) & 3, ksub = k & 7;
    *reinterpret_cast<uint2*>(OutC + ((size_t)(tr * 256 + tk) * 512 + kq * 128 + mrow) * 8 + ksub) = w.u;
  }
}

// ---------- launch ----------
extern "C" void kernel_launch(void* const* d_in, const int* in_sizes, int n_in,
                              void* d_out, int out_size, void* d_ws, size_t ws_size,
                              hipStream_t stream) {
  const float* X     = (const float*)d_in[0];
  const float* cosb  = (const float*)d_in[1];
  const float* sinb  = (const float*)d_in[2];
  const float* Wq    = (const float*)d_in[3];
  const float* Wk    = (const float*)d_in[4];
  const float* Wv    = (const float*)d_in[5];
  const float* Wo    = (const float*)d_in[6];
  const float* sinks = (const float*)d_in[7];

  char* ws = (char*)d_ws;
  u16* Xc    = (u16*)(ws);                 // 16,777,216 B (16x128 tiles)
  u16* WqkvC = (u16*)(ws + 16777216);      // 121,634,816 B (116x128 tiles)
  u16* WoC   = (u16*)(ws);                 // 67,108,864 B (32x256) — reuses Xc/WqkvC after GEMM1
  u16* QKV   = (u16*)(ws + 138412032);     // 60,817,408 B (N-major)
  u16* Qt    = (u16*)(ws + 199229440);     // 50,331,648 B
  u16* Kt    = (u16*)(ws + 249561088);     // 6,291,456 B
  u16* Vc    = (u16*)(ws + 255852544);     // 4,194,304 B (chunked per bh)
  u16* attnC = (u16*)(ws + 260046848);     // 33,554,432 B (16x256 tiles)

  chunk_cvt<<<dim3(16, 128), 256, 0, stream>>>(X, Xc, HID);
  chunk_tr<<<dim3(96, 128), 256, 0, stream>>>(Wq, WqkvC, NH * HD, 128);
  chunk_tr<<<dim3(12, 128), 256, 0, stream>>>(Wk, WqkvC + (size_t)96 * 128 * 4096, NKV * HD, 128);
  chunk_tr<<<dim3(8, 128),  256, 0, stream>>>(Wv, WqkvC + (size_t)108 * 128 * 4096, NKV * VD, 128);
  gemm_chunk<true><<<dim3(16, 116), 256, 0, stream>>>(Xc, WqkvC, QKV, NQKV, 128);
  chunk_tr<<<dim3(32, 256), 256, 0, stream>>>(Wo, WoC, HID, 256);
  rope_kernel<<<2048, 256, 0, stream>>>(QKV, cosb, sinb, Qt, Kt);
  vtr_kernel<<<dim3(2, 16, 16), 256, 0, stream>>>(QKV, Vc);
  attn_kernel<<<dim3(64, 8, 2), 512, 0, stream>>>(Qt, Kt, Vc, sinks, attnC);
  gemm_chunk<false><<<dim3(16, 32), 256, 0, stream>>>(attnC, WoC, d_out, HID, 256);
}

// Round 5
// 973.464 us; speedup vs baseline: 1.4851x; 1.1036x over previous
//
#include <hip/hip_runtime.h>
#include <cstdint>
#include <cstddef>

// ---------- common ----------
typedef unsigned short u16;
typedef __bf16 bf16x8 __attribute__((ext_vector_type(8)));
typedef unsigned short u16x8 __attribute__((ext_vector_type(8)));
typedef float f32x4 __attribute__((ext_vector_type(4)));

typedef const __attribute__((address_space(1))) void* gas_ptr;
typedef __attribute__((address_space(3))) void* las_ptr;
#define GLDS(gp, lp) __builtin_amdgcn_global_load_lds((gas_ptr)(gp), (las_ptr)(lp), 16, 0, 0)

__device__ __forceinline__ u16 f2bf(float f) {
  union { float f; uint32_t u; } a; a.f = f;
  uint32_t u = a.u;
  return (u16)((u + 0x7FFFu + ((u >> 16) & 1u)) >> 16);  // RNE, finite inputs
}
__device__ __forceinline__ float bf2f(u16 h) {
  union { uint32_t u; float f; } a; a.u = ((uint32_t)h) << 16;
  return a.f;
}

// dims
#define BB 2
#define SS 1024
#define HID 4096
#define NH 64
#define NKV 8
#define HD 192
#define VD 128
#define ROT 64
#define WINDOW 128
#define NQKV 14848            // NH*HD + NKV*HD + NKV*VD
#define SCALE 0.07216878364870323f
#define LOG2E 1.4426950408889634f

// Chunked operand layout: tile = 128 rows x 32 k (8192 B), tile (tr,tk) at
// (tr*nkt + tk)*8192 B; within tile chunk c = kq*128 + row (16 B = 8 bf16 of
// row `row`, k = kq*8..+8). MFMA fragment (row r, kq q) = contiguous 16 B.

// ---------- X (f32 MxK) -> chunked bf16 ----------
__global__ __launch_bounds__(256)
void chunk_cvt(const float* __restrict__ src, u16* __restrict__ dst, int K) {
  const int tr = blockIdx.x, tk = blockIdx.y;   // m-tile, k-tile
  const int nkt = K >> 5;
  const int m0 = tr * 128, k0 = tk * 32;
  u16* db = dst + ((size_t)tr * nkt + tk) * 4096;
#pragma unroll
  for (int p = 0; p < 4; ++p) {
    int idx = p * 256 + threadIdx.x;            // 0..1023
    int row = idx >> 3, f4 = idx & 7;
    float4 v = *reinterpret_cast<const float4*>(src + (size_t)(m0 + row) * K + k0 + f4 * 4);
    union { u16 h[4]; uint2 u; } o;
    o.h[0] = f2bf(v.x); o.h[1] = f2bf(v.y); o.h[2] = f2bf(v.z); o.h[3] = f2bf(v.w);
    int kq = f4 >> 1, half = f4 & 1;
    *reinterpret_cast<uint2*>(db + (kq * 128 + row) * 8 + half * 4) = o.u;
  }
}

// ---------- W (f32 RxC, R=K-dim) -> chunked bf16 B^T (C rows x R k) ----------
__global__ __launch_bounds__(256)
void chunk_tr(const float* __restrict__ src, u16* __restrict__ dst, int C, int nkt) {
  __shared__ float lf[32 * 128];                // [k][n] f32, 16 KB
  const int tn = blockIdx.x, tk = blockIdx.y;
  const int n0 = tn * 128, k0 = tk * 32;
#pragma unroll
  for (int p = 0; p < 4; ++p) {
    int idx = p * 256 + threadIdx.x;            // 0..1023
    int kr = idx >> 5, f4 = idx & 31;
    *reinterpret_cast<float4*>(&lf[kr * 128 + f4 * 4]) =
        *reinterpret_cast<const float4*>(src + (size_t)(k0 + kr) * C + n0 + f4 * 4);
  }
  __syncthreads();
  u16* db = dst + ((size_t)tn * nkt + tk) * 4096;
#pragma unroll
  for (int p = 0; p < 2; ++p) {
    int c = p * 256 + threadIdx.x;              // 0..511
    int kq = c >> 7, nl = c & 127;
    union { u16 h[8]; uint4 u; } o;
#pragma unroll
    for (int j = 0; j < 8; ++j) o.h[j] = f2bf(lf[(kq * 8 + j) * 128 + nl]);
    *reinterpret_cast<uint4*>(db + c * 8) = o.u;
  }
}

// ---------- V slices of QKV -> chunked Vc[bh][kq=s/8][d] ----------
__global__ __launch_bounds__(256)
void vtr_kernel(const u16* __restrict__ QKV, u16* __restrict__ Vc) {
  __shared__ u16 lt[64 * 72];                   // [s][d], pad 8 (row = 144 B, 16-mult)
  const int d0 = blockIdx.x * 64, sy = blockIdx.y, bh = blockIdx.z;
  const int b = bh >> 3, h = bh & 7;
  const int s0 = sy * 64;
  const u16* src = QKV + (size_t)(b * SS + s0) * NQKV + (NH * HD + NKV * HD) + h * VD + d0;
#pragma unroll
  for (int p = 0; p < 2; ++p) {
    int idx = p * 256 + threadIdx.x;            // 0..511
    int sl = idx >> 3, f8 = idx & 7;
    *reinterpret_cast<uint4*>(&lt[sl * 72 + f8 * 8]) =
        *reinterpret_cast<const uint4*>(src + (size_t)sl * NQKV + f8 * 8);
  }
  __syncthreads();
  u16* db = Vc + (size_t)bh * 131072;
#pragma unroll
  for (int p = 0; p < 2; ++p) {
    int c = p * 256 + threadIdx.x;              // 0..511
    int kql = c >> 6, dl = c & 63;
    union { u16 h[8]; uint4 u; } o;
#pragma unroll
    for (int j = 0; j < 8; ++j) o.h[j] = lt[(kql * 8 + j) * 72 + dl];
    *reinterpret_cast<uint4*>(db + ((sy * 8 + kql) * 128 + d0 + dl) * 8) = o.u;
  }
}

// ---------- GEMM: C = A(chunked) * B(chunked)^T, LDS-staged, contiguous GLDS ----------
// 128x128 tile, 4 waves (2x2 of 64x64), BK=32 (m97 structure). Staging copies
// one 8KB A-tile + 8KB B-tile with 16 lane-linear GLDS (16 cachelines/instr,
// zero address divergence). Fragment ds_read_b128 are 2-way bank-aliased (free).
template<bool BF16_OUT>
__global__ __launch_bounds__(256, 3)
void gemm_lds(const u16* __restrict__ A, const u16* __restrict__ Bt,
              void* __restrict__ Cout, int N, int nkt) {
  __shared__ alignas(16) char lds[16384];   // A: [0,8192), B: [8192,16384)
  const int tid  = threadIdx.x;
  const int wave = tid >> 6, lane = tid & 63;
  const int quad = lane >> 4, l16 = lane & 15;
  const int m0 = blockIdx.x * 128, n0 = blockIdx.y * 128;
  const int wm = (wave >> 1) * 64, wn = (wave & 1) * 64;

  const u16* Ab = A  + (size_t)blockIdx.x * nkt * 4096;
  const u16* Bb = Bt + (size_t)blockIdx.y * nkt * 4096;

  f32x4 acc[4][4];
#pragma unroll
  for (int i = 0; i < 4; ++i)
#pragma unroll
    for (int j = 0; j < 4; ++j) acc[i][j] = f32x4{0.f, 0.f, 0.f, 0.f};

  for (int kt = 0; kt < nkt; ++kt) {
    const u16* at = Ab + (size_t)kt * 4096;
    const u16* bt = Bb + (size_t)kt * 4096;
    __syncthreads();
#pragma unroll
    for (int p = 0; p < 2; ++p) {
      int c = (wave * 2 + p) * 64;            // chunk base 0..511 step 64
      GLDS(at + (size_t)(c + lane) * 8, &lds[c * 16]);
      GLDS(bt + (size_t)(c + lane) * 8, &lds[8192 + c * 16]);
    }
    __syncthreads();
    bf16x8 af[4], bf[4];
#pragma unroll
    for (int i = 0; i < 4; ++i)
      af[i] = *reinterpret_cast<const bf16x8*>(&lds[(quad * 128 + wm + i * 16 + l16) * 16]);
#pragma unroll
    for (int j = 0; j < 4; ++j)
      bf[j] = *reinterpret_cast<const bf16x8*>(&lds[8192 + (quad * 128 + wn + j * 16 + l16) * 16]);
#pragma unroll
    for (int i = 0; i < 4; ++i)
#pragma unroll
      for (int j = 0; j < 4; ++j)
        acc[i][j] = __builtin_amdgcn_mfma_f32_16x16x32_bf16(af[i], bf[j], acc[i][j], 0, 0, 0);
  }

  // epilogue: C row = quad*4+r, col = l16 (verified m89/m91 layout)
  if constexpr (BF16_OUT) {
    u16* Co = reinterpret_cast<u16*>(Cout);
#pragma unroll
    for (int i = 0; i < 4; ++i)
#pragma unroll
      for (int j = 0; j < 4; ++j)
#pragma unroll
        for (int r = 0; r < 4; ++r)
          Co[(size_t)(m0 + wm + i * 16 + quad * 4 + r) * N + n0 + wn + j * 16 + l16] = f2bf(acc[i][j][r]);
  } else {
    float* Co = reinterpret_cast<float*>(Cout);
#pragma unroll
    for (int i = 0; i < 4; ++i)
#pragma unroll
      for (int j = 0; j < 4; ++j)
#pragma unroll
        for (int r = 0; r < 4; ++r)
          Co[(size_t)(m0 + wm + i * 16 + quad * 4 + r) * N + n0 + wn + j * 16 + l16] = acc[i][j][r];
  }
}

// ---------- RoPE + scatter QK rows -> Q(B,NH,S,HD) K(B,NKV,S,HD), 16B chunks ----------
__global__ __launch_bounds__(256)
void rope_kernel(const u16* __restrict__ QKV, const float* __restrict__ cosb,
                 const float* __restrict__ sinb, u16* __restrict__ Qt,
                 u16* __restrict__ Kt) {
  const int row = blockIdx.x;           // b*1024+s
  const int b = row >> 10, s = row & 1023;
  const u16* xr = QKV + (size_t)row * NQKV;
  const float* cr = cosb + (size_t)row * ROT;
  const float* sr = sinb + (size_t)row * ROT;

  for (int u = threadIdx.x; u < (NH + NKV) * 24; u += 256) {
    const u16* srcb; u16* dstb; int c;
    if (u < NH * 24) {
      int h = u / 24; c = u - h * 24;
      srcb = xr + h * HD;
      dstb = Qt + ((size_t)(b * NH + h) * SS + s) * HD;
    } else {
      int v = u - NH * 24; int h = v / 24; c = v - h * 24;
      srcb = xr + NH * HD + h * HD;
      dstb = Kt + ((size_t)(b * NKV + h) * SS + s) * HD;
    }
    int d0 = c * 8;
    if (c < 8) {
      u16x8 xv = *reinterpret_cast<const u16x8*>(srcb + d0);
      u16x8 pv = *reinterpret_cast<const u16x8*>(srcb + ((c ^ 4) * 8));
      float4 c0 = *reinterpret_cast<const float4*>(cr + d0);
      float4 c1 = *reinterpret_cast<const float4*>(cr + d0 + 4);
      float4 s0 = *reinterpret_cast<const float4*>(sr + d0);
      float4 s1 = *reinterpret_cast<const float4*>(sr + d0 + 4);
      float cs[8] = {c0.x, c0.y, c0.z, c0.w, c1.x, c1.y, c1.z, c1.w};
      float sn[8] = {s0.x, s0.y, s0.z, s0.w, s1.x, s1.y, s1.z, s1.w};
      float sgn = (c < 4) ? -1.f : 1.f;
      union { u16 h[8]; uint4 u4; } o;
#pragma unroll
      for (int j = 0; j < 8; ++j)
        o.h[j] = f2bf(bf2f(xv[j]) * cs[j] + sgn * bf2f(pv[j]) * sn[j]);
      *reinterpret_cast<uint4*>(dstb + d0) = o.u4;
    } else {
      *reinterpret_cast<uint4*>(dstb + d0) = *reinterpret_cast<const uint4*>(srcb + d0);
    }
  }
}

// ---------- attention: wg = (qtile16, hkv, b); 8 waves = 8 q-heads ----------
// Out written in GEMM2's chunked-A layout.
__global__ __launch_bounds__(512, 1)
void attn_kernel(const u16* __restrict__ Qt, const u16* __restrict__ Kt,
                 const u16* __restrict__ Vc, const float* __restrict__ sinks,
                 u16* __restrict__ OutC) {
  __shared__ alignas(16) char vlds[40960];   // chunk(kq,d) @ (kq*128+d)*16, kq 0..19
  __shared__ alignas(16) char plds[8][1024]; // per-wave P fragment staging
  __shared__ float llds[8][16];

  const int qt = blockIdx.x, hkv = blockIdx.y, b = blockIdx.z;
  const int tid = threadIdx.x;
  const int wave = tid >> 6, lane = tid & 63;
  const int quad = lane >> 4, l16 = lane & 15;
  const int h = hkv * 8 + wave;
  const int q0 = qt * 16, k0 = q0 - 128;
  const int kq0 = (q0 - 128) >> 3;           // exact (q0 mult of 16)

  // stage V window: contiguous chunked copy (clamped at edges)
  const u16* Vb = Vc + (size_t)(b * NKV + hkv) * 131072;
  for (int it = 0; it < 5; ++it) {
    int c = (it * 8 + wave) * 64 + lane;     // 0..2559
    int kql = c >> 7, d = c & 127;
    int kqc = min(max(kq0 + kql, 0), 127);
    GLDS(Vb + (kqc * 128 + d) * 8, &vlds[(it * 8 + wave) * 1024]);
  }
  // Q fragments (A-operand): lane holds Q[q=l16][k=quad*8+j] per 32-chunk
  const u16* Qb = Qt + ((size_t)(b * NH + h) * SS + q0) * HD;
  bf16x8 qf[6];
#pragma unroll
  for (int c = 0; c < 6; ++c)
    qf[c] = *reinterpret_cast<const bf16x8*>(Qb + (size_t)l16 * HD + c * 32 + quad * 8);
  const float sinkv = sinks[h];
  __syncthreads();

  // S = Q K^T : 9 key tiles of 16
  const u16* Kb = Kt + (size_t)(b * NKV + hkv) * SS * HD;
  f32x4 sc[9];
#pragma unroll
  for (int kt = 0; kt < 9; ++kt) {
    int key = k0 + kt * 16 + l16;
    int keyc = min(max(key, 0), SS - 1);
    const u16* Krow = Kb + (size_t)keyc * HD;
    f32x4 s4 = {0.f, 0.f, 0.f, 0.f};
#pragma unroll
    for (int c = 0; c < 6; ++c) {
      bf16x8 kf = *reinterpret_cast<const bf16x8*>(Krow + c * 32 + quad * 8);
      s4 = __builtin_amdgcn_mfma_f32_16x16x32_bf16(qf[c], kf, s4, 0, 0, 0);
    }
    sc[kt] = s4;
  }

  // softmax per row (row = q0 + quad*4 + r); sink folded into max & denom
#pragma unroll
  for (int r = 0; r < 4; ++r) {
    int q = q0 + quad * 4 + r;
    float mv = sinkv;
    float svs[9];
#pragma unroll
    for (int kt = 0; kt < 9; ++kt) {
      int key = k0 + kt * 16 + l16;
      bool valid = (key >= 0) && (key <= q) && (q - key < WINDOW);
      float sv = valid ? sc[kt][r] * SCALE : -3.0e38f;
      svs[kt] = sv;
      mv = fmaxf(mv, sv);
    }
#pragma unroll
    for (int off = 1; off < 16; off <<= 1) mv = fmaxf(mv, __shfl_xor(mv, off));
    float lsum = 0.f;
#pragma unroll
    for (int kt = 0; kt < 9; ++kt) {
      float p = exp2f((svs[kt] - mv) * LOG2E);
      sc[kt][r] = p;
      lsum += p;
    }
#pragma unroll
    for (int off = 1; off < 16; off <<= 1) lsum += __shfl_xor(lsum, off);
    lsum += exp2f((sinkv - mv) * LOG2E);
    if (l16 == 0) llds[wave][quad * 4 + r] = lsum;
  }

  // O^T = V^T P^T over 5 key-chunks of 32 (tile 9 of P zero-padded)
  f32x4 oacc[8];
#pragma unroll
  for (int mt = 0; mt < 8; ++mt) oacc[mt] = f32x4{0.f, 0.f, 0.f, 0.f};
#pragma unroll
  for (int c = 0; c < 5; ++c) {
#pragma unroll
    for (int t = 0; t < 2; ++t) {
      int kt = 2 * c + t;
#pragma unroll
      for (int r = 0; r < 4; ++r) {
        float p = (kt < 9) ? sc[kt][r] : 0.f;
        int off = (((t * 2 + (l16 >> 3)) * 16 + quad * 4 + r) << 4) + ((l16 & 7) << 1);
        *reinterpret_cast<u16*>(&plds[wave][off]) = f2bf(p);
      }
    }
    // same-wave LDS ops execute in order: write->read safe without barrier
    bf16x8 pf = *reinterpret_cast<const bf16x8*>(&plds[wave][(quad * 16 + l16) << 4]);
#pragma unroll
    for (int mt = 0; mt < 8; ++mt) {
      bf16x8 vf = *reinterpret_cast<const bf16x8*>(&vlds[((c * 4 + quad) * 128 + mt * 16 + l16) << 4]);
      oacc[mt] = __builtin_amdgcn_mfma_f32_16x16x32_bf16(vf, pf, oacc[mt], 0, 0, 0);
    }
  }

  // write O into GEMM2's chunked-A layout (M=2048, K=8192, nkt=256)
  float rl = 1.0f / llds[wave][l16];
  int m = b * SS + q0 + l16;
  int tr = m >> 7, mrow = m & 127;
#pragma unroll
  for (int mt = 0; mt < 8; ++mt) {
    union { u16 h4[4]; uint2 u; } w;
#pragma unroll
    for (int r = 0; r < 4; ++r) w.h4[r] = f2bf(oacc[mt][r] * rl);
    int k = h * VD + mt * 16 + quad * 4;
    int tk = k >> 5, kq = (k >> 3) & 3, ksub = k & 7;
    *reinterpret_cast<uint2*>(OutC + ((size_t)(tr * 256 + tk) * 512 + kq * 128 + mrow) * 8 + ksub) = w.u;
  }
}

// ---------- launch ----------
extern "C" void kernel_launch(void* const* d_in, const int* in_sizes, int n_in,
                              void* d_out, int out_size, void* d_ws, size_t ws_size,
                              hipStream_t stream) {
  const float* X     = (const float*)d_in[0];
  const float* cosb  = (const float*)d_in[1];
  const float* sinb  = (const float*)d_in[2];
  const float* Wq    = (const float*)d_in[3];
  const float* Wk    = (const float*)d_in[4];
  const float* Wv    = (const float*)d_in[5];
  const float* Wo    = (const float*)d_in[6];
  const float* sinks = (const float*)d_in[7];

  char* ws = (char*)d_ws;
  u16* Xc    = (u16*)(ws);                 // 16,777,216 B (16x128 tiles)
  u16* WqkvC = (u16*)(ws + 16777216);      // 121,634,816 B (116x128 tiles)
  u16* WoC   = (u16*)(ws);                 // 67,108,864 B (32x256) — reuses Xc/WqkvC after GEMM1
  u16* QKV   = (u16*)(ws + 138412032);     // 60,817,408 B (N-major)
  u16* Qt    = (u16*)(ws + 199229440);     // 50,331,648 B
  u16* Kt    = (u16*)(ws + 249561088);     // 6,291,456 B
  u16* Vc    = (u16*)(ws + 255852544);     // 4,194,304 B (chunked per bh)
  u16* attnC = (u16*)(ws + 260046848);     // 33,554,432 B (16x256 tiles)

  chunk_cvt<<<dim3(16, 128), 256, 0, stream>>>(X, Xc, HID);
  chunk_tr<<<dim3(96, 128), 256, 0, stream>>>(Wq, WqkvC, NH * HD, 128);
  chunk_tr<<<dim3(12, 128), 256, 0, stream>>>(Wk, WqkvC + (size_t)96 * 128 * 4096, NKV * HD, 128);
  chunk_tr<<<dim3(8, 128),  256, 0, stream>>>(Wv, WqkvC + (size_t)108 * 128 * 4096, NKV * VD, 128);
  gemm_lds<true><<<dim3(16, 116), 256, 0, stream>>>(Xc, WqkvC, QKV, NQKV, 128);
  chunk_tr<<<dim3(32, 256), 256, 0, stream>>>(Wo, WoC, HID, 256);
  rope_kernel<<<2048, 256, 0, stream>>>(QKV, cosb, sinb, Qt, Kt);
  vtr_kernel<<<dim3(2, 16, 16), 256, 0, stream>>>(QKV, Vc);
  attn_kernel<<<dim3(64, 8, 2), 512, 0, stream>>>(Qt, Kt, Vc, sinks, attnC);
  gemm_lds<false><<<dim3(16, 32), 256, 0, stream>>>(attnC, WoC, d_out, HID, 256);
}